// Round 1
// baseline (689.747 us; speedup 1.0000x reference)
//
#include <hip/hip_runtime.h>
#include <math.h>

// SubsetOperator: K=16 iterations of relaxed top-k (Gumbel softmax subset).
// B=2048 rows, N=16384 cols, fp32. One block (1024 threads) per row; all
// state (s, khot) lives in registers: 16 elements per thread.
//
// Per iteration:
//   m = rowmax(s); e = exp(s - m); Z = rowsum(e)
//   oh = e / Z; khot += oh; s += log(max(1 - oh, EPS))

#define N_COLS   16384
#define K_ITERS  16
#define NTHREADS 1024
#define EPT      (N_COLS / NTHREADS)   // 16 elements per thread
#define V4       (EPT / 4)             // 4 float4 chunks per thread

__global__ __launch_bounds__(NTHREADS, 1)
void subset_topk_kernel(const float* __restrict__ scores,
                        const float* __restrict__ g,
                        float* __restrict__ out)
{
    __shared__ float red[17];   // [0..15] wave partials, [16] final broadcast

    const int tid  = threadIdx.x;
    const int lane = tid & 63;
    const int wid  = tid >> 6;            // 16 waves per block
    const size_t base = (size_t)blockIdx.x * N_COLS;

    const float4* s4 = (const float4*)(scores + base);
    const float4* g4 = (const float4*)(g + base);
    float4*       o4 = (float4*)(out + base);

    float s[EPT], khot[EPT];

    // Load: interleaved float4 layout for perfect coalescing.
    // Thread t, chunk j -> float4 index j*NTHREADS + t.
    #pragma unroll
    for (int j = 0; j < V4; ++j) {
        float4 a = s4[j * NTHREADS + tid];
        float4 b = g4[j * NTHREADS + tid];
        s[j*4+0] = a.x + b.x;
        s[j*4+1] = a.y + b.y;
        s[j*4+2] = a.z + b.z;
        s[j*4+3] = a.w + b.w;
        khot[j*4+0] = 0.f; khot[j*4+1] = 0.f;
        khot[j*4+2] = 0.f; khot[j*4+3] = 0.f;
    }

    const float EPSV = 1.17549435e-38f;   // np.finfo(float32).tiny

    for (int it = 0; it < K_ITERS; ++it) {
        // ---- row max ----
        float m = -3.402823466e+38f;
        #pragma unroll
        for (int j = 0; j < EPT; ++j) m = fmaxf(m, s[j]);
        #pragma unroll
        for (int o = 32; o > 0; o >>= 1) m = fmaxf(m, __shfl_down(m, o, 64));
        if (lane == 0) red[wid] = m;
        __syncthreads();
        if (wid == 0) {
            float v = red[lane & 15];
            #pragma unroll
            for (int o = 8; o > 0; o >>= 1) v = fmaxf(v, __shfl_down(v, o, 64));
            if (lane == 0) red[16] = v;
        }
        __syncthreads();
        m = red[16];

        // ---- exp + row sum ----
        float e[EPT];
        float z = 0.f;
        #pragma unroll
        for (int j = 0; j < EPT; ++j) {
            e[j] = __expf(s[j] - m);      // TAU = 1.0
            z += e[j];
        }
        #pragma unroll
        for (int o = 32; o > 0; o >>= 1) z += __shfl_down(z, o, 64);
        if (lane == 0) red[wid] = z;
        __syncthreads();
        if (wid == 0) {
            float v = red[lane & 15];
            #pragma unroll
            for (int o = 8; o > 0; o >>= 1) v += __shfl_down(v, o, 64);
            if (lane == 0) red[16] = v;
        }
        __syncthreads();
        z = red[16];

        // ---- normalize, accumulate khot, apply mask to s ----
        const float inv = 1.0f / z;
        #pragma unroll
        for (int j = 0; j < EPT; ++j) {
            float oh = e[j] * inv;
            khot[j] += oh;
            s[j] += __logf(fmaxf(1.0f - oh, EPSV));
        }
    }

    // Store khot
    #pragma unroll
    for (int j = 0; j < V4; ++j) {
        float4 r;
        r.x = khot[j*4+0]; r.y = khot[j*4+1];
        r.z = khot[j*4+2]; r.w = khot[j*4+3];
        o4[j * NTHREADS + tid] = r;
    }
}

extern "C" void kernel_launch(void* const* d_in, const int* in_sizes, int n_in,
                              void* d_out, int out_size, void* d_ws, size_t ws_size,
                              hipStream_t stream) {
    const float* scores = (const float*)d_in[0];
    const float* g      = (const float*)d_in[1];
    float* out          = (float*)d_out;

    const int rows = in_sizes[0] / N_COLS;   // 2048
    subset_topk_kernel<<<rows, NTHREADS, 0, stream>>>(scores, g, out);
}

// Round 2
// 337.722 us; speedup vs baseline: 2.0424x; 2.0424x over previous
//
#include <hip/hip_runtime.h>
#include <math.h>

// SubsetOperator: K=16 rounds of relaxed top-k (Gumbel softmax subset).
// B=2048 rows, N=16384 cols, fp32. One block (1024 threads) per row.
//
// Key algebraic identity: the reference's
//     s += log(max(1 - onehot, EPS));  onehot = softmax(s)
// is equivalent, in exp-domain, to
//     e *= max(1 - onehot, EPS);       onehot = e / sum(e)
// so per-thread state is just e[16], khot[16] (32 floats -> registers),
// and the inner loop has ZERO transcendentals:
//     oh = e*inv; khot += oh; e *= max(1-oh,EPS); z_next += e
// (6 VALU ops / element / iteration). One sum-reduction per iteration,
// double-buffered LDS partials -> 1 barrier per iteration.

#define N_COLS   16384
#define K_ITERS  16
#define NTHREADS 1024
#define EPT      (N_COLS / NTHREADS)   // 16 elements per thread
#define V4       (EPT / 4)             // 4 float4 chunks per thread

__global__ __launch_bounds__(NTHREADS, 4)
void subset_topk_kernel(const float* __restrict__ scores,
                        const float* __restrict__ g,
                        float* __restrict__ out)
{
    __shared__ __align__(16) float red[2][16];  // per-wave partials, double-buffered

    const int tid  = threadIdx.x;
    const int lane = tid & 63;
    const int wid  = tid >> 6;                  // 16 waves per block
    const size_t base = (size_t)blockIdx.x * N_COLS;

    const float4* s4 = (const float4*)(scores + base);
    const float4* g4 = (const float4*)(g + base);
    float4*       o4 = (float4*)(out + base);

    const float EPSV = 1.17549435e-38f;         // np.finfo(float32).tiny

    float e[EPT], khot[EPT];
    float zloc = 0.f;

    // Load (interleaved float4 for coalescing), go straight to exp-domain.
    #pragma unroll
    for (int j = 0; j < V4; ++j) {
        float4 a = s4[j * NTHREADS + tid];
        float4 b = g4[j * NTHREADS + tid];
        float e0 = __expf(a.x + b.x);
        float e1 = __expf(a.y + b.y);
        float e2 = __expf(a.z + b.z);
        float e3 = __expf(a.w + b.w);
        e[j*4+0] = e0; e[j*4+1] = e1; e[j*4+2] = e2; e[j*4+3] = e3;
        zloc += (e0 + e1) + (e2 + e3);
        khot[j*4+0] = 0.f; khot[j*4+1] = 0.f;
        khot[j*4+2] = 0.f; khot[j*4+3] = 0.f;
    }

    #pragma unroll 1
    for (int it = 0; it < K_ITERS; ++it) {
        // ---- block-wide sum of zloc ----
        float z = zloc;
        #pragma unroll
        for (int o = 32; o > 0; o >>= 1) z += __shfl_xor(z, o, 64);
        if (lane == 0) red[it & 1][wid] = z;
        __syncthreads();
        // every thread sums the 16 wave partials (uniform -> LDS broadcast)
        const float4* r4 = (const float4*)red[it & 1];
        float4 p0 = r4[0], p1 = r4[1], p2 = r4[2], p3 = r4[3];
        z = (((p0.x + p0.y) + (p0.z + p0.w)) + ((p1.x + p1.y) + (p1.z + p1.w)))
          + (((p2.x + p2.y) + (p2.z + p2.w)) + ((p3.x + p3.y) + (p3.z + p3.w)));

        const float inv = 1.0f / z;

        // ---- normalize, accumulate khot, apply mask in exp-domain ----
        zloc = 0.f;
        #pragma unroll
        for (int j = 0; j < EPT; ++j) {
            float oh = e[j] * inv;
            khot[j] += oh;
            float en = e[j] * fmaxf(1.0f - oh, EPSV);
            e[j] = en;
            zloc += en;
        }
    }

    // Store khot
    #pragma unroll
    for (int j = 0; j < V4; ++j) {
        float4 r;
        r.x = khot[j*4+0]; r.y = khot[j*4+1];
        r.z = khot[j*4+2]; r.w = khot[j*4+3];
        o4[j * NTHREADS + tid] = r;
    }
}

extern "C" void kernel_launch(void* const* d_in, const int* in_sizes, int n_in,
                              void* d_out, int out_size, void* d_ws, size_t ws_size,
                              hipStream_t stream) {
    const float* scores = (const float*)d_in[0];
    const float* g      = (const float*)d_in[1];
    float* out          = (float*)d_out;

    const int rows = in_sizes[0] / N_COLS;   // 2048
    subset_topk_kernel<<<rows, NTHREADS, 0, stream>>>(scores, g, out);
}

// Round 3
// 336.730 us; speedup vs baseline: 2.0484x; 1.0029x over previous
//
#include <hip/hip_runtime.h>
#include <math.h>

// SubsetOperator: K=16 rounds of relaxed top-k (Gumbel softmax subset).
// B=2048 rows, N=16384 cols, fp32. One block (1024 threads) per row.
//
// Exp-domain identity: s += log(max(1-oh,EPS)); softmax(s)  ==  e *= (1-oh); e/sum(e)
// Inner loop per element per iteration (4 VALU ops, 0 transcendentals):
//     t = e*inv; khot += t; e = fmaf(-t, e, e); z += e
// The EPS clamp is dropped: it only binds when 1-oh rounds <= 0, where both
// the reference and this kernel produce |e_new| <= e*ulp -> khot error ~1e-7.
// inv via v_rcp_f32 (1 ulp), not the full IEEE divide sequence.

#define N_COLS   16384
#define K_ITERS  16
#define NTHREADS 1024
#define EPT      (N_COLS / NTHREADS)   // 16 elements per thread
#define V4       (EPT / 4)             // 4 float4 chunks per thread

__global__ __launch_bounds__(NTHREADS, 4)
void subset_topk_kernel(const float* __restrict__ scores,
                        const float* __restrict__ g,
                        float* __restrict__ out)
{
    __shared__ float red[2][16];        // per-wave partials, double-buffered

    const int tid  = threadIdx.x;
    const int lane = tid & 63;
    const int wid  = tid >> 6;          // 16 waves per block
    const size_t base = (size_t)blockIdx.x * N_COLS;

    const float4* s4 = (const float4*)(scores + base);
    const float4* g4 = (const float4*)(g + base);
    float4*       o4 = (float4*)(out + base);

    float e[EPT], khot[EPT];
    float zloc = 0.f;

    // Load (interleaved float4 for coalescing), go straight to exp-domain.
    #pragma unroll
    for (int j = 0; j < V4; ++j) {
        float4 a = s4[j * NTHREADS + tid];
        float4 b = g4[j * NTHREADS + tid];
        float e0 = __expf(a.x + b.x);
        float e1 = __expf(a.y + b.y);
        float e2 = __expf(a.z + b.z);
        float e3 = __expf(a.w + b.w);
        e[j*4+0] = e0; e[j*4+1] = e1; e[j*4+2] = e2; e[j*4+3] = e3;
        zloc += (e0 + e1) + (e2 + e3);
        khot[j*4+0] = 0.f; khot[j*4+1] = 0.f;
        khot[j*4+2] = 0.f; khot[j*4+3] = 0.f;
    }

    #pragma unroll 1
    for (int it = 0; it < K_ITERS; ++it) {
        // ---- wave-local sum ----
        float z = zloc;
        #pragma unroll
        for (int o = 32; o > 0; o >>= 1) z += __shfl_xor(z, o, 64);
        if (lane == 0) red[it & 1][wid] = z;
        __syncthreads();

        // ---- cross-wave: lane l reads partial (l&15), 4-step xor-sum of 16 ----
        float v = red[it & 1][lane & 15];   // same-address broadcast per 16-lane group
        #pragma unroll
        for (int o = 1; o < 16; o <<= 1) v += __shfl_xor(v, o, 64);

        const float inv = __builtin_amdgcn_rcpf(v);

        // ---- 4-op inner loop ----
        zloc = 0.f;
        #pragma unroll
        for (int j = 0; j < EPT; ++j) {
            float t = e[j] * inv;           // oh
            khot[j] += t;
            float en = fmaf(-t, e[j], e[j]); // e*(1-oh), no clamp
            e[j] = en;
            zloc += en;
        }
    }

    // Store khot
    #pragma unroll
    for (int j = 0; j < V4; ++j) {
        float4 r;
        r.x = khot[j*4+0]; r.y = khot[j*4+1];
        r.z = khot[j*4+2]; r.w = khot[j*4+3];
        o4[j * NTHREADS + tid] = r;
    }
}

extern "C" void kernel_launch(void* const* d_in, const int* in_sizes, int n_in,
                              void* d_out, int out_size, void* d_ws, size_t ws_size,
                              hipStream_t stream) {
    const float* scores = (const float*)d_in[0];
    const float* g      = (const float*)d_in[1];
    float* out          = (float*)d_out;

    const int rows = in_sizes[0] / N_COLS;   // 2048
    subset_topk_kernel<<<rows, NTHREADS, 0, stream>>>(scores, g, out);
}